// Round 10
// baseline (105.345 us; speedup 1.0000x reference)
//
#include <hip/hip_runtime.h>

#define AS1 __attribute__((address_space(1)))
#define AS3 __attribute__((address_space(3)))

typedef float f32x4 __attribute__((ext_vector_type(4)));
typedef long lx2 __attribute__((ext_vector_type(2)));

static constexpr int C = 768;
static constexpr int NB = 128;    // N1 == N2
static constexpr int S  = 256;    // W*H
static constexpr int XY_ELEMS  = NB * NB * S;  // 4194304
static constexpr int XSQ_ELEMS = NB * S;       // 32768
static constexpr size_t WS_TENSOR_B = (size_t)S * NB * C;  // bytes (fp8)

// ---------------------------------------------------------------------------
// Pass 1 (sequential-read restructure; R9 had tensor=b>>9 bug, fixed to
// b/768): block = (tensor, n, 128-c range). 8 chunks of 16c x 256s — every
// global read is a contiguous 1KB wave-run (tests DRAM row-efficiency
// theory vs the old 256B@1KB-stride pattern).
// LDS [16][256] f32 dbuf; thread owns s=t in the store phase, emits fp8 e4m3
// in the SAME pre-permuted k-tile layout pass2 expects:
//   slot(u) = 2*((u&3)^sn) + (u>>2), u=(c>>3)&7, kt=c>>6, sn=(n>>1)&3.
// Square-mean: per-thread over its 128 c -> one atomicAdd (6 blocks/target;
// reorder noise ~1e-7 << threshold).
// ---------------------------------------------------------------------------
__global__ __launch_bounds__(256) void pass1(const float* __restrict__ x,
                                             const float* __restrict__ y,
                                             unsigned char* __restrict__ xb,
                                             unsigned char* __restrict__ yb,
                                             float* __restrict__ out) {
  const int b      = blockIdx.x;          // 1536 = 2 * 128 * 6
  const int tensor = b / 768;             // FIXED (was b>>9)
  const int local  = b - tensor * 768;
  const int n      = local / 6;           // 0..127
  const int cr     = local - n * 6;       // 0..5 (128-c range)

  const float*   src = tensor ? y  : x;
  unsigned char* dst = tensor ? yb : xb;
  float*         sqo = out + XY_ELEMS + tensor * XSQ_ELEMS;

  __shared__ float tile[2][16 * 256];     // 2 x 16 KB

  const int t    = threadIdx.x;
  const int w    = t >> 6;                // wave id: read-side row offset
  const int lane = t & 63;
  const int sn   = (n >> 1) & 3;

  const float* srcn = src + (size_t)n * (C * S) + (size_t)(cr * 128) * S;
  unsigned char* dstrow = dst + ((size_t)t * NB + n) * C;  // s = t

  float sq = 0.f;
  f32x4 cur[4], nxt[4];

  // prologue: chunk 0 — 4 x 1KB contiguous wave-runs
#pragma unroll
  for (int i = 0; i < 4; ++i)
    cur[i] = __builtin_nontemporal_load(reinterpret_cast<const f32x4*>(
        srcn + (size_t)(i * 4 + w) * S + lane * 4));

#pragma unroll
  for (int ch = 0; ch < 8; ++ch) {
    float* tb = tile[ch & 1];

    if (ch < 7) {  // prefetch next chunk (stays ahead of cur's vmcnt wait)
#pragma unroll
      for (int i = 0; i < 4; ++i)
        nxt[i] = __builtin_nontemporal_load(reinterpret_cast<const f32x4*>(
            srcn + (size_t)((ch + 1) * 16 + i * 4 + w) * S + lane * 4));
    }

    // LDS write: row (i*4+w), 16B per lane, conflict-free
#pragma unroll
    for (int i = 0; i < 4; ++i)
      *reinterpret_cast<f32x4*>(&tb[(i * 4 + w) * 256 + lane * 4]) = cur[i];

    asm volatile("s_waitcnt lgkmcnt(0)" ::: "memory");
    __builtin_amdgcn_s_barrier();

    // transposed read: column s=t, 16 c values (bank = t%32, 2-way = free)
    float f[16];
#pragma unroll
    for (int i = 0; i < 16; ++i) f[i] = tb[i * 256 + t];
#pragma unroll
    for (int i = 0; i < 16; ++i) sq += f[i] * f[i];

    // fp8 e4m3 pack: two 8B units, permuted slot store
    int w0 = __builtin_amdgcn_cvt_pk_fp8_f32(f[0], f[1], 0, false);
    w0     = __builtin_amdgcn_cvt_pk_fp8_f32(f[2], f[3], w0, true);
    int w1 = __builtin_amdgcn_cvt_pk_fp8_f32(f[4], f[5], 0, false);
    w1     = __builtin_amdgcn_cvt_pk_fp8_f32(f[6], f[7], w1, true);
    int w2 = __builtin_amdgcn_cvt_pk_fp8_f32(f[8], f[9], 0, false);
    w2     = __builtin_amdgcn_cvt_pk_fp8_f32(f[10], f[11], w2, true);
    int w3 = __builtin_amdgcn_cvt_pk_fp8_f32(f[12], f[13], 0, false);
    w3     = __builtin_amdgcn_cvt_pk_fp8_f32(f[14], f[15], w3, true);

    const int c0 = cr * 128 + ch * 16;
    const int kt = c0 >> 6;
    const int u0 = (c0 >> 3) & 7;          // first 8B unit (even)
    const int s0 = 2 * ((u0 & 3) ^ sn) + (u0 >> 2);
    const int u1 = u0 + 1;                 // second unit
    const int s1 = 2 * ((u1 & 3) ^ sn) + (u1 >> 2);
    *reinterpret_cast<uint2*>(dstrow + kt * 64 + s0 * 8) =
        make_uint2((unsigned)w0, (unsigned)w1);
    *reinterpret_cast<uint2*>(dstrow + kt * 64 + s1 * 8) =
        make_uint2((unsigned)w2, (unsigned)w3);

#pragma unroll
    for (int i = 0; i < 4; ++i) cur[i] = nxt[i];
  }

  atomicAdd(&sqo[n * S + t], sq * (1.0f / 768.0f));
}

// ---------------------------------------------------------------------------
// Pass 2 (frozen from R7/R8): per s, fp8 e4m3 128x128x768 GEMM; epilogue
// writes contiguous fp32 ws2[s][m][n] in full 64B lines.
// ---------------------------------------------------------------------------
__global__ __launch_bounds__(256) void pass2(const unsigned char* __restrict__ xb,
                                             const unsigned char* __restrict__ yb,
                                             float* __restrict__ ws2) {
  const int bid = blockIdx.x;
  const int s = ((bid & 7) << 5) | (bid >> 3);  // XCD-aware, bijective

  const unsigned char* A = xb + (size_t)s * (NB * C);
  const unsigned char* B = yb + (size_t)s * (NB * C);

  __shared__ unsigned char As[2][128 * 64];
  __shared__ unsigned char Bs[2][128 * 64];

  const int t    = threadIdx.x;
  const int lane = t & 63;
  const int w    = t >> 6;
  const int wn   = w >> 1;
  const int wm   = w & 1;

  const unsigned char* gA[2];
  const unsigned char* gB[2];
  int lo16[2];
#pragma unroll
  for (int i = 0; i < 2; ++i) {
    int ci  = i * 256 + t;
    int row = ci >> 2;
    int j16 = ci & 3;
    gA[i]   = A + row * C + j16 * 16;
    gB[i]   = B + row * C + j16 * 16;
    lo16[i] = ci * 16;
  }

#define STAGE(K0, BUF)                                                        \
  {                                                                           \
    _Pragma("unroll") for (int i = 0; i < 2; ++i) {                           \
      __builtin_amdgcn_global_load_lds(                                       \
          (const AS1 unsigned int*)(gA[i] + (K0)*64),                         \
          (AS3 unsigned int*)((char*)As[BUF] + lo16[i]), 16, 0, 0);           \
      __builtin_amdgcn_global_load_lds(                                       \
          (const AS1 unsigned int*)(gB[i] + (K0)*64),                         \
          (AS3 unsigned int*)((char*)Bs[BUF] + lo16[i]), 16, 0, 0);           \
    }                                                                         \
  }

  f32x4 acc[4][4] = {};

  STAGE(0, 0);

#pragma unroll
  for (int k0 = 0; k0 < 12; ++k0) {
    if (k0 < 11) STAGE(k0 + 1, (k0 + 1) & 1);

    if (k0 < 11) {
      asm volatile("s_waitcnt vmcnt(4)" ::: "memory");
    } else {
      asm volatile("s_waitcnt vmcnt(0)" ::: "memory");
    }
    __builtin_amdgcn_s_barrier();

    const char* Ab = (const char*)As[k0 & 1];
    const char* Bb = (const char*)Bs[k0 & 1];

    lx2 av[4], bv[4];
    const int q = lane >> 4;
#pragma unroll
    for (int mi = 0; mi < 4; ++mi) {
      int row = wn * 64 + mi * 16 + (lane & 15);
      av[mi] = *reinterpret_cast<const lx2*>(
          Ab + row * 64 + ((q ^ ((row >> 1) & 3)) * 16));
    }
#pragma unroll
    for (int nj = 0; nj < 4; ++nj) {
      int row = wm * 64 + nj * 16 + (lane & 15);
      bv[nj] = *reinterpret_cast<const lx2*>(
          Bb + row * 64 + ((q ^ ((row >> 1) & 3)) * 16));
    }
#pragma unroll
    for (int mi = 0; mi < 4; ++mi)
#pragma unroll
      for (int nj = 0; nj < 4; ++nj) {
        acc[mi][nj] = __builtin_amdgcn_mfma_f32_16x16x32_fp8_fp8(
            av[mi][0], bv[nj][0], acc[mi][nj], 0, 0, 0);
        acc[mi][nj] = __builtin_amdgcn_mfma_f32_16x16x32_fp8_fp8(
            av[mi][1], bv[nj][1], acc[mi][nj], 0, 0, 0);
      }

    if (k0 < 11) __builtin_amdgcn_s_barrier();
  }
#undef STAGE

  const float inv = 1.0f / 768.0f;
  float* w2 = ws2 + (size_t)s * (NB * NB);
#pragma unroll
  for (int mi = 0; mi < 4; ++mi) {
#pragma unroll
    for (int nj = 0; nj < 4; ++nj) {
      f32x4 v = acc[mi][nj] * inv;
      int mm = wm * 64 + nj * 16 + (lane & 15);
      int nn = wn * 64 + mi * 16 + (lane >> 4) * 4;
      *reinterpret_cast<f32x4*>(w2 + (size_t)mm * NB + nn) = v;
    }
  }
}

// ---------------------------------------------------------------------------
// Pass 3 (frozen from R8): transpose ws2[s][m][n] -> out[n][m][s].
// ---------------------------------------------------------------------------
__global__ __launch_bounds__(256) void pass3(const float* __restrict__ ws2,
                                             float* __restrict__ out) {
  const int bid = blockIdx.x;        // 1024 blocks
  const int m   = bid & 127;
  const int st  = (bid >> 7) & 3;
  const int nt  = bid >> 9;          // 0..1
  const int t   = threadIdx.x;
  const int l16 = t & 15;
  const int hi4 = t >> 4;

  __shared__ float tile[64 * 64];    // swizzled [s][nchunk^((s>>2)&15)][4]

  const float* src = ws2 + ((size_t)(st * 64) * NB + m) * NB + nt * 64;
#pragma unroll
  for (int i = 0; i < 4; ++i) {
    int s_local = hi4 + 16 * i;
    f32x4 v = *reinterpret_cast<const f32x4*>(
        src + (size_t)s_local * (NB * NB) + l16 * 4);
    int chunk = l16 ^ ((s_local >> 2) & 15);
    *reinterpret_cast<f32x4*>(&tile[s_local * 64 + chunk * 4]) = v;
  }
  __syncthreads();

  float* dst = out + ((size_t)(nt * 64) * NB + m) * S + st * 64;
#pragma unroll
  for (int i = 0; i < 4; ++i) {
    int n_local = hi4 + 16 * i;
    int cb      = (n_local >> 2) & 15;
    int ne      = n_local & 3;
    int s4      = l16 * 4;
    f32x4 v;
#pragma unroll
    for (int j = 0; j < 4; ++j) {
      int ss = s4 + j;
      v[j] = tile[ss * 64 + ((cb ^ ((ss >> 2) & 15)) << 2) + ne];
    }
    __builtin_nontemporal_store(
        v, reinterpret_cast<f32x4*>(dst + (size_t)n_local * (NB * S) + s4));
  }
}

extern "C" void kernel_launch(void* const* d_in, const int* in_sizes, int n_in,
                              void* d_out, int out_size, void* d_ws, size_t ws_size,
                              hipStream_t stream) {
  const float* x = (const float*)d_in[0];
  const float* y = (const float*)d_in[1];
  float* out = (float*)d_out;

  unsigned char* xb = (unsigned char*)d_ws;       // [256][128][768] fp8
  unsigned char* yb = xb + WS_TENSOR_B;
  float* ws2 = (float*)((char*)d_ws + 2 * WS_TENSOR_B);  // [256][128][128] f32

  // zero xx/yy (atomicAdd target)
  hipMemsetAsync(out + XY_ELEMS, 0, (size_t)2 * XSQ_ELEMS * sizeof(float),
                 stream);
  pass1<<<1536, 256, 0, stream>>>(x, y, xb, yb, out);
  pass2<<<256, 256, 0, stream>>>(xb, yb, ws2);
  pass3<<<1024, 256, 0, stream>>>(ws2, out);
}

// Round 11
// 83.584 us; speedup vs baseline: 1.2603x; 1.2603x over previous
//
#include <hip/hip_runtime.h>

#define AS1 __attribute__((address_space(1)))
#define AS3 __attribute__((address_space(3)))

typedef float f32x4 __attribute__((ext_vector_type(4)));
typedef long lx2 __attribute__((ext_vector_type(2)));

static constexpr int C = 768;
static constexpr int NB = 128;    // N1 == N2
static constexpr int S  = 256;    // W*H
static constexpr int XY_ELEMS  = NB * NB * S;  // 4194304
static constexpr int XSQ_ELEMS = NB * S;       // 32768
static constexpr size_t WS_TENSOR_B = (size_t)S * NB * C;  // bytes (fp8)

// ---------------------------------------------------------------------------
// Pass 1: sequential-read + register-stash full-line writes.
// block = (tensor, n, 128-c range); 8 chunks of 16c x 256s — every global
// read is a contiguous 1KB wave-run. Thread owns s=t; fp8 pairs accumulate
// in uint2 pr[8] (static indices) across the 4 chunks of each 64-c k-tile,
// then ONE 64B burst (4 x dwordx4, line fully dirty at once — fixes R10's
// 2x write amplification). sn-permutation applied on the store ADDRESS
// ((q^sn)*16, block-uniform sn) -> ws bytes identical to R7/R8/R10 layout:
//   slot(u) = 2*((u&3)^sn) + (u>>2), u=(c>>3)&7, kt=c>>6, sn=(n>>1)&3.
// ---------------------------------------------------------------------------
__global__ __launch_bounds__(256) void pass1(const float* __restrict__ x,
                                             const float* __restrict__ y,
                                             unsigned char* __restrict__ xb,
                                             unsigned char* __restrict__ yb,
                                             float* __restrict__ out) {
  const int b      = blockIdx.x;          // 1536 = 2 * 128 * 6
  const int tensor = b / 768;
  const int local  = b - tensor * 768;
  const int n      = local / 6;           // 0..127
  const int cr     = local - n * 6;       // 0..5 (128-c range)

  const float*   src = tensor ? y  : x;
  unsigned char* dst = tensor ? yb : xb;
  float*         sqo = out + XY_ELEMS + tensor * XSQ_ELEMS;

  __shared__ float tile[2][16 * 256];     // 2 x 16 KB

  const int t    = threadIdx.x;
  const int w    = t >> 6;                // wave id: read-side row offset
  const int lane = t & 63;
  const int sn   = (n >> 1) & 3;

  const float* srcn = src + (size_t)n * (C * S) + (size_t)(cr * 128) * S;
  unsigned char* dstrow = dst + ((size_t)t * NB + n) * C;  // s = t

  float sq = 0.f;
  f32x4 cur[4], nxt[4];
  uint2 pr[8];                            // 64B k-tile stash (static idx)

  // prologue: chunk 0 — 4 x 1KB contiguous wave-runs
#pragma unroll
  for (int i = 0; i < 4; ++i)
    cur[i] = __builtin_nontemporal_load(reinterpret_cast<const f32x4*>(
        srcn + (size_t)(i * 4 + w) * S + lane * 4));

#pragma unroll
  for (int ch = 0; ch < 8; ++ch) {
    float* tb = tile[ch & 1];

    if (ch < 7) {  // prefetch next chunk (stays ahead of cur's vmcnt wait)
#pragma unroll
      for (int i = 0; i < 4; ++i)
        nxt[i] = __builtin_nontemporal_load(reinterpret_cast<const f32x4*>(
            srcn + (size_t)((ch + 1) * 16 + i * 4 + w) * S + lane * 4));
    }

    // LDS write: row (i*4+w), 16B per lane, conflict-free
#pragma unroll
    for (int i = 0; i < 4; ++i)
      *reinterpret_cast<f32x4*>(&tb[(i * 4 + w) * 256 + lane * 4]) = cur[i];

    asm volatile("s_waitcnt lgkmcnt(0)" ::: "memory");
    __builtin_amdgcn_s_barrier();

    // transposed read: column s=t, 16 c values (bank = t%32, 2-way = free)
    float f[16];
#pragma unroll
    for (int i = 0; i < 16; ++i) f[i] = tb[i * 256 + t];
#pragma unroll
    for (int i = 0; i < 16; ++i) sq += f[i] * f[i];

    // fp8 e4m3 pack: two 8B units -> stash at static indices
    int w0 = __builtin_amdgcn_cvt_pk_fp8_f32(f[0], f[1], 0, false);
    w0     = __builtin_amdgcn_cvt_pk_fp8_f32(f[2], f[3], w0, true);
    int w1 = __builtin_amdgcn_cvt_pk_fp8_f32(f[4], f[5], 0, false);
    w1     = __builtin_amdgcn_cvt_pk_fp8_f32(f[6], f[7], w1, true);
    int w2 = __builtin_amdgcn_cvt_pk_fp8_f32(f[8], f[9], 0, false);
    w2     = __builtin_amdgcn_cvt_pk_fp8_f32(f[10], f[11], w2, true);
    int w3 = __builtin_amdgcn_cvt_pk_fp8_f32(f[12], f[13], 0, false);
    w3     = __builtin_amdgcn_cvt_pk_fp8_f32(f[14], f[15], w3, true);

    pr[(ch & 3) * 2]     = make_uint2((unsigned)w0, (unsigned)w1);
    pr[(ch & 3) * 2 + 1] = make_uint2((unsigned)w2, (unsigned)w3);

    if ((ch & 3) == 3) {
      // k-tile complete: 64B burst. group g=q^sn holds units {q, q+4}
      // (inverse of slot(u)); all pr indices compile-time.
      const int kt = cr * 2 + (ch >> 2);
#pragma unroll
      for (int q = 0; q < 4; ++q) {
        uint4 v = make_uint4(pr[q].x, pr[q].y, pr[q + 4].x, pr[q + 4].y);
        *reinterpret_cast<uint4*>(dstrow + kt * 64 + ((q ^ sn) * 16)) = v;
      }
    }

#pragma unroll
    for (int i = 0; i < 4; ++i) cur[i] = nxt[i];
  }

  atomicAdd(&sqo[n * S + t], sq * (1.0f / 768.0f));
}

// ---------------------------------------------------------------------------
// Pass 2 (frozen from R7/R8): per s, fp8 e4m3 128x128x768 GEMM; epilogue
// writes contiguous fp32 ws2[s][m][n] in full 64B lines.
// ---------------------------------------------------------------------------
__global__ __launch_bounds__(256) void pass2(const unsigned char* __restrict__ xb,
                                             const unsigned char* __restrict__ yb,
                                             float* __restrict__ ws2) {
  const int bid = blockIdx.x;
  const int s = ((bid & 7) << 5) | (bid >> 3);  // XCD-aware, bijective

  const unsigned char* A = xb + (size_t)s * (NB * C);
  const unsigned char* B = yb + (size_t)s * (NB * C);

  __shared__ unsigned char As[2][128 * 64];
  __shared__ unsigned char Bs[2][128 * 64];

  const int t    = threadIdx.x;
  const int lane = t & 63;
  const int w    = t >> 6;
  const int wn   = w >> 1;
  const int wm   = w & 1;

  const unsigned char* gA[2];
  const unsigned char* gB[2];
  int lo16[2];
#pragma unroll
  for (int i = 0; i < 2; ++i) {
    int ci  = i * 256 + t;
    int row = ci >> 2;
    int j16 = ci & 3;
    gA[i]   = A + row * C + j16 * 16;
    gB[i]   = B + row * C + j16 * 16;
    lo16[i] = ci * 16;
  }

#define STAGE(K0, BUF)                                                        \
  {                                                                           \
    _Pragma("unroll") for (int i = 0; i < 2; ++i) {                           \
      __builtin_amdgcn_global_load_lds(                                       \
          (const AS1 unsigned int*)(gA[i] + (K0)*64),                         \
          (AS3 unsigned int*)((char*)As[BUF] + lo16[i]), 16, 0, 0);           \
      __builtin_amdgcn_global_load_lds(                                       \
          (const AS1 unsigned int*)(gB[i] + (K0)*64),                         \
          (AS3 unsigned int*)((char*)Bs[BUF] + lo16[i]), 16, 0, 0);           \
    }                                                                         \
  }

  f32x4 acc[4][4] = {};

  STAGE(0, 0);

#pragma unroll
  for (int k0 = 0; k0 < 12; ++k0) {
    if (k0 < 11) STAGE(k0 + 1, (k0 + 1) & 1);

    if (k0 < 11) {
      asm volatile("s_waitcnt vmcnt(4)" ::: "memory");
    } else {
      asm volatile("s_waitcnt vmcnt(0)" ::: "memory");
    }
    __builtin_amdgcn_s_barrier();

    const char* Ab = (const char*)As[k0 & 1];
    const char* Bb = (const char*)Bs[k0 & 1];

    lx2 av[4], bv[4];
    const int q = lane >> 4;
#pragma unroll
    for (int mi = 0; mi < 4; ++mi) {
      int row = wn * 64 + mi * 16 + (lane & 15);
      av[mi] = *reinterpret_cast<const lx2*>(
          Ab + row * 64 + ((q ^ ((row >> 1) & 3)) * 16));
    }
#pragma unroll
    for (int nj = 0; nj < 4; ++nj) {
      int row = wm * 64 + nj * 16 + (lane & 15);
      bv[nj] = *reinterpret_cast<const lx2*>(
          Bb + row * 64 + ((q ^ ((row >> 1) & 3)) * 16));
    }
#pragma unroll
    for (int mi = 0; mi < 4; ++mi)
#pragma unroll
      for (int nj = 0; nj < 4; ++nj) {
        acc[mi][nj] = __builtin_amdgcn_mfma_f32_16x16x32_fp8_fp8(
            av[mi][0], bv[nj][0], acc[mi][nj], 0, 0, 0);
        acc[mi][nj] = __builtin_amdgcn_mfma_f32_16x16x32_fp8_fp8(
            av[mi][1], bv[nj][1], acc[mi][nj], 0, 0, 0);
      }

    if (k0 < 11) __builtin_amdgcn_s_barrier();
  }
#undef STAGE

  const float inv = 1.0f / 768.0f;
  float* w2 = ws2 + (size_t)s * (NB * NB);
#pragma unroll
  for (int mi = 0; mi < 4; ++mi) {
#pragma unroll
    for (int nj = 0; nj < 4; ++nj) {
      f32x4 v = acc[mi][nj] * inv;
      int mm = wm * 64 + nj * 16 + (lane & 15);
      int nn = wn * 64 + mi * 16 + (lane >> 4) * 4;
      *reinterpret_cast<f32x4*>(w2 + (size_t)mm * NB + nn) = v;
    }
  }
}

// ---------------------------------------------------------------------------
// Pass 3 (frozen from R8): transpose ws2[s][m][n] -> out[n][m][s].
// ---------------------------------------------------------------------------
__global__ __launch_bounds__(256) void pass3(const float* __restrict__ ws2,
                                             float* __restrict__ out) {
  const int bid = blockIdx.x;        // 1024 blocks
  const int m   = bid & 127;
  const int st  = (bid >> 7) & 3;
  const int nt  = bid >> 9;          // 0..1
  const int t   = threadIdx.x;
  const int l16 = t & 15;
  const int hi4 = t >> 4;

  __shared__ float tile[64 * 64];    // swizzled [s][nchunk^((s>>2)&15)][4]

  const float* src = ws2 + ((size_t)(st * 64) * NB + m) * NB + nt * 64;
#pragma unroll
  for (int i = 0; i < 4; ++i) {
    int s_local = hi4 + 16 * i;
    f32x4 v = *reinterpret_cast<const f32x4*>(
        src + (size_t)s_local * (NB * NB) + l16 * 4);
    int chunk = l16 ^ ((s_local >> 2) & 15);
    *reinterpret_cast<f32x4*>(&tile[s_local * 64 + chunk * 4]) = v;
  }
  __syncthreads();

  float* dst = out + ((size_t)(nt * 64) * NB + m) * S + st * 64;
#pragma unroll
  for (int i = 0; i < 4; ++i) {
    int n_local = hi4 + 16 * i;
    int cb      = (n_local >> 2) & 15;
    int ne      = n_local & 3;
    int s4      = l16 * 4;
    f32x4 v;
#pragma unroll
    for (int j = 0; j < 4; ++j) {
      int ss = s4 + j;
      v[j] = tile[ss * 64 + ((cb ^ ((ss >> 2) & 15)) << 2) + ne];
    }
    __builtin_nontemporal_store(
        v, reinterpret_cast<f32x4*>(dst + (size_t)n_local * (NB * S) + s4));
  }
}

extern "C" void kernel_launch(void* const* d_in, const int* in_sizes, int n_in,
                              void* d_out, int out_size, void* d_ws, size_t ws_size,
                              hipStream_t stream) {
  const float* x = (const float*)d_in[0];
  const float* y = (const float*)d_in[1];
  float* out = (float*)d_out;

  unsigned char* xb = (unsigned char*)d_ws;       // [256][128][768] fp8
  unsigned char* yb = xb + WS_TENSOR_B;
  float* ws2 = (float*)((char*)d_ws + 2 * WS_TENSOR_B);  // [256][128][128] f32

  // zero xx/yy (atomicAdd target)
  hipMemsetAsync(out + XY_ELEMS, 0, (size_t)2 * XSQ_ELEMS * sizeof(float),
                 stream);
  pass1<<<1536, 256, 0, stream>>>(x, y, xb, yb, out);
  pass2<<<256, 256, 0, stream>>>(xb, yb, ws2);
  pass3<<<1024, 256, 0, stream>>>(ws2, out);
}

// Round 12
// 79.304 us; speedup vs baseline: 1.3284x; 1.0540x over previous
//
#include <hip/hip_runtime.h>

#define AS1 __attribute__((address_space(1)))
#define AS3 __attribute__((address_space(3)))

typedef float f32x4 __attribute__((ext_vector_type(4)));
typedef long lx2 __attribute__((ext_vector_type(2)));

static constexpr int C = 768;
static constexpr int NB = 128;    // N1 == N2
static constexpr int S  = 256;    // W*H
static constexpr int XY_ELEMS  = NB * NB * S;  // 4194304
static constexpr int XSQ_ELEMS = NB * S;       // 32768
static constexpr size_t WS_TENSOR_B = (size_t)S * NB * C;  // bytes (fp8)

// ---------------------------------------------------------------------------
// Pass 1 (R11 structure frozen; ONLY ws layout changed to [n][s][c]):
// block = (tensor, n, 128-c range); 8 chunks of 16c x 256s, sequential 1KB
// read runs, register-stash 64B bursts. ws write now confined to the block's
// 192KB n-slab (lane stride 768B, not 98KB); block map n = nIdx*8 + (b&7)
// makes the 6 cr-siblings of each n launch-adjacent AND co-XCD so they fill
// each 768B row concurrently -> dense DRAM writeback rows.
// fp8 unit permutation within each 64B k-tile unchanged:
//   slot(u) = 2*((u&3)^sn) + (u>>2), u=(c>>3)&7, kt=c>>6, sn=(n>>1)&3.
// ---------------------------------------------------------------------------
__global__ __launch_bounds__(256) void pass1(const float* __restrict__ x,
                                             const float* __restrict__ y,
                                             unsigned char* __restrict__ xb,
                                             unsigned char* __restrict__ yb,
                                             float* __restrict__ out) {
  const int b    = blockIdx.x;            // 1536 = 8 XCD * 192
  const int x8   = b & 7;                 // XCD
  const int j    = b >> 3;                // 0..191
  const int tensor = j / 96;
  const int r    = j - tensor * 96;
  const int nIdx = r / 6;                 // 0..15
  const int cr   = r - nIdx * 6;          // 0..5 (128-c range)
  const int n    = nIdx * 8 + x8;         // 0..127

  const float*   src = tensor ? y  : x;
  unsigned char* dst = tensor ? yb : xb;
  float*         sqo = out + XY_ELEMS + tensor * XSQ_ELEMS;

  __shared__ float tile[2][16 * 256];     // 2 x 16 KB

  const int t    = threadIdx.x;
  const int w    = t >> 6;                // wave id: read-side row offset
  const int lane = t & 63;
  const int sn   = (n >> 1) & 3;

  const float* srcn = src + (size_t)n * (C * S) + (size_t)(cr * 128) * S;
  unsigned char* dstrow = dst + (size_t)n * (S * C) + (size_t)t * C;  // s = t

  float sq = 0.f;
  f32x4 cur[4], nxt[4];
  uint2 pr[8];                            // 64B k-tile stash (static idx)

  // prologue: chunk 0 — 4 x 1KB contiguous wave-runs
#pragma unroll
  for (int i = 0; i < 4; ++i)
    cur[i] = __builtin_nontemporal_load(reinterpret_cast<const f32x4*>(
        srcn + (size_t)(i * 4 + w) * S + lane * 4));

#pragma unroll
  for (int ch = 0; ch < 8; ++ch) {
    float* tb = tile[ch & 1];

    if (ch < 7) {  // prefetch next chunk (stays ahead of cur's vmcnt wait)
#pragma unroll
      for (int i = 0; i < 4; ++i)
        nxt[i] = __builtin_nontemporal_load(reinterpret_cast<const f32x4*>(
            srcn + (size_t)((ch + 1) * 16 + i * 4 + w) * S + lane * 4));
    }

    // LDS write: row (i*4+w), 16B per lane, conflict-free
#pragma unroll
    for (int i = 0; i < 4; ++i)
      *reinterpret_cast<f32x4*>(&tb[(i * 4 + w) * 256 + lane * 4]) = cur[i];

    asm volatile("s_waitcnt lgkmcnt(0)" ::: "memory");
    __builtin_amdgcn_s_barrier();

    // transposed read: column s=t, 16 c values (bank = t%32, 2-way = free)
    float f[16];
#pragma unroll
    for (int i = 0; i < 16; ++i) f[i] = tb[i * 256 + t];
#pragma unroll
    for (int i = 0; i < 16; ++i) sq += f[i] * f[i];

    // fp8 e4m3 pack: two 8B units -> stash at static indices
    int w0 = __builtin_amdgcn_cvt_pk_fp8_f32(f[0], f[1], 0, false);
    w0     = __builtin_amdgcn_cvt_pk_fp8_f32(f[2], f[3], w0, true);
    int w1 = __builtin_amdgcn_cvt_pk_fp8_f32(f[4], f[5], 0, false);
    w1     = __builtin_amdgcn_cvt_pk_fp8_f32(f[6], f[7], w1, true);
    int w2 = __builtin_amdgcn_cvt_pk_fp8_f32(f[8], f[9], 0, false);
    w2     = __builtin_amdgcn_cvt_pk_fp8_f32(f[10], f[11], w2, true);
    int w3 = __builtin_amdgcn_cvt_pk_fp8_f32(f[12], f[13], 0, false);
    w3     = __builtin_amdgcn_cvt_pk_fp8_f32(f[14], f[15], w3, true);

    pr[(ch & 3) * 2]     = make_uint2((unsigned)w0, (unsigned)w1);
    pr[(ch & 3) * 2 + 1] = make_uint2((unsigned)w2, (unsigned)w3);

    if ((ch & 3) == 3) {
      // k-tile complete: 64B burst. group g=q^sn holds units {q, q+4}
      const int kt = cr * 2 + (ch >> 2);
#pragma unroll
      for (int q = 0; q < 4; ++q) {
        uint4 v = make_uint4(pr[q].x, pr[q].y, pr[q + 4].x, pr[q + 4].y);
        *reinterpret_cast<uint4*>(dstrow + kt * 64 + ((q ^ sn) * 16)) = v;
      }
    }

#pragma unroll
    for (int i = 0; i < 4; ++i) cur[i] = nxt[i];
  }

  atomicAdd(&sqo[n * S + t], sq * (1.0f / 768.0f));
}

// ---------------------------------------------------------------------------
// Pass 2 (loop frozen from R7/R8; ONLY staging addresses changed for the
// [n][s][c] ws layout: row stride S*C, s-offset s*C): per s, fp8 e4m3
// 128x128x768 GEMM; epilogue writes contiguous fp32 ws2[s][m][n].
// ---------------------------------------------------------------------------
__global__ __launch_bounds__(256) void pass2(const unsigned char* __restrict__ xb,
                                             const unsigned char* __restrict__ yb,
                                             float* __restrict__ ws2) {
  const int bid = blockIdx.x;
  const int s = ((bid & 7) << 5) | (bid >> 3);  // XCD-aware, bijective

  const unsigned char* A = xb + (size_t)s * C;  // [n][s][c]: + n*(S*C)
  const unsigned char* B = yb + (size_t)s * C;

  __shared__ unsigned char As[2][128 * 64];
  __shared__ unsigned char Bs[2][128 * 64];

  const int t    = threadIdx.x;
  const int lane = t & 63;
  const int w    = t >> 6;
  const int wn   = w >> 1;
  const int wm   = w & 1;

  const unsigned char* gA[2];
  const unsigned char* gB[2];
  int lo16[2];
#pragma unroll
  for (int i = 0; i < 2; ++i) {
    int ci  = i * 256 + t;
    int row = ci >> 2;                  // n
    int j16 = ci & 3;
    gA[i]   = A + (size_t)row * (S * C) + j16 * 16;
    gB[i]   = B + (size_t)row * (S * C) + j16 * 16;
    lo16[i] = ci * 16;
  }

#define STAGE(K0, BUF)                                                        \
  {                                                                           \
    _Pragma("unroll") for (int i = 0; i < 2; ++i) {                           \
      __builtin_amdgcn_global_load_lds(                                       \
          (const AS1 unsigned int*)(gA[i] + (K0)*64),                         \
          (AS3 unsigned int*)((char*)As[BUF] + lo16[i]), 16, 0, 0);           \
      __builtin_amdgcn_global_load_lds(                                       \
          (const AS1 unsigned int*)(gB[i] + (K0)*64),                         \
          (AS3 unsigned int*)((char*)Bs[BUF] + lo16[i]), 16, 0, 0);           \
    }                                                                         \
  }

  f32x4 acc[4][4] = {};

  STAGE(0, 0);

#pragma unroll
  for (int k0 = 0; k0 < 12; ++k0) {
    if (k0 < 11) STAGE(k0 + 1, (k0 + 1) & 1);

    if (k0 < 11) {
      asm volatile("s_waitcnt vmcnt(4)" ::: "memory");
    } else {
      asm volatile("s_waitcnt vmcnt(0)" ::: "memory");
    }
    __builtin_amdgcn_s_barrier();

    const char* Ab = (const char*)As[k0 & 1];
    const char* Bb = (const char*)Bs[k0 & 1];

    lx2 av[4], bv[4];
    const int q = lane >> 4;
#pragma unroll
    for (int mi = 0; mi < 4; ++mi) {
      int row = wn * 64 + mi * 16 + (lane & 15);
      av[mi] = *reinterpret_cast<const lx2*>(
          Ab + row * 64 + ((q ^ ((row >> 1) & 3)) * 16));
    }
#pragma unroll
    for (int nj = 0; nj < 4; ++nj) {
      int row = wm * 64 + nj * 16 + (lane & 15);
      bv[nj] = *reinterpret_cast<const lx2*>(
          Bb + row * 64 + ((q ^ ((row >> 1) & 3)) * 16));
    }
#pragma unroll
    for (int mi = 0; mi < 4; ++mi)
#pragma unroll
      for (int nj = 0; nj < 4; ++nj) {
        acc[mi][nj] = __builtin_amdgcn_mfma_f32_16x16x32_fp8_fp8(
            av[mi][0], bv[nj][0], acc[mi][nj], 0, 0, 0);
        acc[mi][nj] = __builtin_amdgcn_mfma_f32_16x16x32_fp8_fp8(
            av[mi][1], bv[nj][1], acc[mi][nj], 0, 0, 0);
      }

    if (k0 < 11) __builtin_amdgcn_s_barrier();
  }
#undef STAGE

  const float inv = 1.0f / 768.0f;
  float* w2 = ws2 + (size_t)s * (NB * NB);
#pragma unroll
  for (int mi = 0; mi < 4; ++mi) {
#pragma unroll
    for (int nj = 0; nj < 4; ++nj) {
      f32x4 v = acc[mi][nj] * inv;
      int mm = wm * 64 + nj * 16 + (lane & 15);
      int nn = wn * 64 + mi * 16 + (lane >> 4) * 4;
      *reinterpret_cast<f32x4*>(w2 + (size_t)mm * NB + nn) = v;
    }
  }
}

// ---------------------------------------------------------------------------
// Pass 3 (frozen from R8): transpose ws2[s][m][n] -> out[n][m][s].
// ---------------------------------------------------------------------------
__global__ __launch_bounds__(256) void pass3(const float* __restrict__ ws2,
                                             float* __restrict__ out) {
  const int bid = blockIdx.x;        // 1024 blocks
  const int m   = bid & 127;
  const int st  = (bid >> 7) & 3;
  const int nt  = bid >> 9;          // 0..1
  const int t   = threadIdx.x;
  const int l16 = t & 15;
  const int hi4 = t >> 4;

  __shared__ float tile[64 * 64];    // swizzled [s][nchunk^((s>>2)&15)][4]

  const float* src = ws2 + ((size_t)(st * 64) * NB + m) * NB + nt * 64;
#pragma unroll
  for (int i = 0; i < 4; ++i) {
    int s_local = hi4 + 16 * i;
    f32x4 v = *reinterpret_cast<const f32x4*>(
        src + (size_t)s_local * (NB * NB) + l16 * 4);
    int chunk = l16 ^ ((s_local >> 2) & 15);
    *reinterpret_cast<f32x4*>(&tile[s_local * 64 + chunk * 4]) = v;
  }
  __syncthreads();

  float* dst = out + ((size_t)(nt * 64) * NB + m) * S + st * 64;
#pragma unroll
  for (int i = 0; i < 4; ++i) {
    int n_local = hi4 + 16 * i;
    int cb      = (n_local >> 2) & 15;
    int ne      = n_local & 3;
    int s4      = l16 * 4;
    f32x4 v;
#pragma unroll
    for (int j = 0; j < 4; ++j) {
      int ss = s4 + j;
      v[j] = tile[ss * 64 + ((cb ^ ((ss >> 2) & 15)) << 2) + ne];
    }
    __builtin_nontemporal_store(
        v, reinterpret_cast<f32x4*>(dst + (size_t)n_local * (NB * S) + s4));
  }
}

extern "C" void kernel_launch(void* const* d_in, const int* in_sizes, int n_in,
                              void* d_out, int out_size, void* d_ws, size_t ws_size,
                              hipStream_t stream) {
  const float* x = (const float*)d_in[0];
  const float* y = (const float*)d_in[1];
  float* out = (float*)d_out;

  unsigned char* xb = (unsigned char*)d_ws;       // [128][256][768] fp8
  unsigned char* yb = xb + WS_TENSOR_B;
  float* ws2 = (float*)((char*)d_ws + 2 * WS_TENSOR_B);  // [256][128][128] f32

  // zero xx/yy (atomicAdd target)
  hipMemsetAsync(out + XY_ELEMS, 0, (size_t)2 * XSQ_ELEMS * sizeof(float),
                 stream);
  pass1<<<1536, 256, 0, stream>>>(x, y, xb, yb, out);
  pass2<<<256, 256, 0, stream>>>(xb, yb, ws2);
  pass3<<<1024, 256, 0, stream>>>(ws2, out);
}

// Round 13
// 69.154 us; speedup vs baseline: 1.5233x; 1.1468x over previous
//
#include <hip/hip_runtime.h>

#define AS1 __attribute__((address_space(1)))
#define AS3 __attribute__((address_space(3)))

typedef float f32x4 __attribute__((ext_vector_type(4)));
typedef long lx2 __attribute__((ext_vector_type(2)));
typedef unsigned short u16x4 __attribute__((ext_vector_type(4)));

static constexpr int C = 768;
static constexpr int NB = 128;    // N1 == N2
static constexpr int S  = 256;    // W*H
static constexpr int XY_ELEMS  = NB * NB * S;  // 4194304
static constexpr int XSQ_ELEMS = NB * S;       // 32768
static constexpr size_t WS_TENSOR_B = (size_t)S * NB * C;  // bytes (fp8)

// ---------------------------------------------------------------------------
// Pass 1 (R12 structure frozen; ONLY change: plain loads, no nontemporal —
// tests whether nt was hurting x/y L3 residency across replays).
// block = (tensor, n, 128-c range); ws layout [n][s][c] fp8, pre-permuted:
//   slot(u) = 2*((u&3)^sn) + (u>>2), u=(c>>3)&7, kt=c>>6, sn=(n>>1)&3.
// ---------------------------------------------------------------------------
__global__ __launch_bounds__(256) void pass1(const float* __restrict__ x,
                                             const float* __restrict__ y,
                                             unsigned char* __restrict__ xb,
                                             unsigned char* __restrict__ yb,
                                             float* __restrict__ out) {
  const int b    = blockIdx.x;            // 1536 = 8 XCD * 192
  const int x8   = b & 7;                 // XCD
  const int j    = b >> 3;                // 0..191
  const int tensor = j / 96;
  const int r    = j - tensor * 96;
  const int nIdx = r / 6;                 // 0..15
  const int cr   = r - nIdx * 6;          // 0..5 (128-c range)
  const int n    = nIdx * 8 + x8;         // 0..127

  const float*   src = tensor ? y  : x;
  unsigned char* dst = tensor ? yb : xb;
  float*         sqo = out + XY_ELEMS + tensor * XSQ_ELEMS;

  __shared__ float tile[2][16 * 256];     // 2 x 16 KB

  const int t    = threadIdx.x;
  const int w    = t >> 6;                // wave id: read-side row offset
  const int lane = t & 63;
  const int sn   = (n >> 1) & 3;

  const float* srcn = src + (size_t)n * (C * S) + (size_t)(cr * 128) * S;
  unsigned char* dstrow = dst + (size_t)n * (S * C) + (size_t)t * C;  // s = t

  float sq = 0.f;
  f32x4 cur[4], nxt[4];
  uint2 pr[8];                            // 64B k-tile stash (static idx)

  // prologue: chunk 0 — 4 x 1KB contiguous wave-runs
#pragma unroll
  for (int i = 0; i < 4; ++i)
    cur[i] = *reinterpret_cast<const f32x4*>(
        srcn + (size_t)(i * 4 + w) * S + lane * 4);

#pragma unroll
  for (int ch = 0; ch < 8; ++ch) {
    float* tb = tile[ch & 1];

    if (ch < 7) {  // prefetch next chunk
#pragma unroll
      for (int i = 0; i < 4; ++i)
        nxt[i] = *reinterpret_cast<const f32x4*>(
            srcn + (size_t)((ch + 1) * 16 + i * 4 + w) * S + lane * 4);
    }

    // LDS write: row (i*4+w), 16B per lane, conflict-free
#pragma unroll
    for (int i = 0; i < 4; ++i)
      *reinterpret_cast<f32x4*>(&tb[(i * 4 + w) * 256 + lane * 4]) = cur[i];

    asm volatile("s_waitcnt lgkmcnt(0)" ::: "memory");
    __builtin_amdgcn_s_barrier();

    // transposed read: column s=t, 16 c values (2-way bank = free)
    float f[16];
#pragma unroll
    for (int i = 0; i < 16; ++i) f[i] = tb[i * 256 + t];
#pragma unroll
    for (int i = 0; i < 16; ++i) sq += f[i] * f[i];

    // fp8 e4m3 pack: two 8B units -> stash at static indices
    int w0 = __builtin_amdgcn_cvt_pk_fp8_f32(f[0], f[1], 0, false);
    w0     = __builtin_amdgcn_cvt_pk_fp8_f32(f[2], f[3], w0, true);
    int w1 = __builtin_amdgcn_cvt_pk_fp8_f32(f[4], f[5], 0, false);
    w1     = __builtin_amdgcn_cvt_pk_fp8_f32(f[6], f[7], w1, true);
    int w2 = __builtin_amdgcn_cvt_pk_fp8_f32(f[8], f[9], 0, false);
    w2     = __builtin_amdgcn_cvt_pk_fp8_f32(f[10], f[11], w2, true);
    int w3 = __builtin_amdgcn_cvt_pk_fp8_f32(f[12], f[13], 0, false);
    w3     = __builtin_amdgcn_cvt_pk_fp8_f32(f[14], f[15], w3, true);

    pr[(ch & 3) * 2]     = make_uint2((unsigned)w0, (unsigned)w1);
    pr[(ch & 3) * 2 + 1] = make_uint2((unsigned)w2, (unsigned)w3);

    if ((ch & 3) == 3) {
      // k-tile complete: 64B burst. group g=q^sn holds units {q, q+4}
      const int kt = cr * 2 + (ch >> 2);
#pragma unroll
      for (int q = 0; q < 4; ++q) {
        uint4 v = make_uint4(pr[q].x, pr[q].y, pr[q + 4].x, pr[q + 4].y);
        *reinterpret_cast<uint4*>(dstrow + kt * 64 + ((q ^ sn) * 16)) = v;
      }
    }

#pragma unroll
    for (int i = 0; i < 4; ++i) cur[i] = nxt[i];
  }

  atomicAdd(&sqo[n * S + t], sq * (1.0f / 768.0f));
}

// ---------------------------------------------------------------------------
// Pass 2 (loop frozen; epilogue now packs bf16 -> ws2b[s][m][n], halving the
// intermediate write traffic; full 64B lines still formed per wave-store).
// ---------------------------------------------------------------------------
__global__ __launch_bounds__(256) void pass2(const unsigned char* __restrict__ xb,
                                             const unsigned char* __restrict__ yb,
                                             unsigned short* __restrict__ ws2b) {
  const int bid = blockIdx.x;
  const int s = ((bid & 7) << 5) | (bid >> 3);  // XCD-aware, bijective

  const unsigned char* A = xb + (size_t)s * C;  // [n][s][c]: + n*(S*C)
  const unsigned char* B = yb + (size_t)s * C;

  __shared__ unsigned char As[2][128 * 64];
  __shared__ unsigned char Bs[2][128 * 64];

  const int t    = threadIdx.x;
  const int lane = t & 63;
  const int w    = t >> 6;
  const int wn   = w >> 1;
  const int wm   = w & 1;

  const unsigned char* gA[2];
  const unsigned char* gB[2];
  int lo16[2];
#pragma unroll
  for (int i = 0; i < 2; ++i) {
    int ci  = i * 256 + t;
    int row = ci >> 2;                  // n
    int j16 = ci & 3;
    gA[i]   = A + (size_t)row * (S * C) + j16 * 16;
    gB[i]   = B + (size_t)row * (S * C) + j16 * 16;
    lo16[i] = ci * 16;
  }

#define STAGE(K0, BUF)                                                        \
  {                                                                           \
    _Pragma("unroll") for (int i = 0; i < 2; ++i) {                           \
      __builtin_amdgcn_global_load_lds(                                       \
          (const AS1 unsigned int*)(gA[i] + (K0)*64),                         \
          (AS3 unsigned int*)((char*)As[BUF] + lo16[i]), 16, 0, 0);           \
      __builtin_amdgcn_global_load_lds(                                       \
          (const AS1 unsigned int*)(gB[i] + (K0)*64),                         \
          (AS3 unsigned int*)((char*)Bs[BUF] + lo16[i]), 16, 0, 0);           \
    }                                                                         \
  }

  f32x4 acc[4][4] = {};

  STAGE(0, 0);

#pragma unroll
  for (int k0 = 0; k0 < 12; ++k0) {
    if (k0 < 11) STAGE(k0 + 1, (k0 + 1) & 1);

    if (k0 < 11) {
      asm volatile("s_waitcnt vmcnt(4)" ::: "memory");
    } else {
      asm volatile("s_waitcnt vmcnt(0)" ::: "memory");
    }
    __builtin_amdgcn_s_barrier();

    const char* Ab = (const char*)As[k0 & 1];
    const char* Bb = (const char*)Bs[k0 & 1];

    lx2 av[4], bv[4];
    const int q = lane >> 4;
#pragma unroll
    for (int mi = 0; mi < 4; ++mi) {
      int row = wn * 64 + mi * 16 + (lane & 15);
      av[mi] = *reinterpret_cast<const lx2*>(
          Ab + row * 64 + ((q ^ ((row >> 1) & 3)) * 16));
    }
#pragma unroll
    for (int nj = 0; nj < 4; ++nj) {
      int row = wm * 64 + nj * 16 + (lane & 15);
      bv[nj] = *reinterpret_cast<const lx2*>(
          Bb + row * 64 + ((q ^ ((row >> 1) & 3)) * 16));
    }
#pragma unroll
    for (int mi = 0; mi < 4; ++mi)
#pragma unroll
      for (int nj = 0; nj < 4; ++nj) {
        acc[mi][nj] = __builtin_amdgcn_mfma_f32_16x16x32_fp8_fp8(
            av[mi][0], bv[nj][0], acc[mi][nj], 0, 0, 0);
        acc[mi][nj] = __builtin_amdgcn_mfma_f32_16x16x32_fp8_fp8(
            av[mi][1], bv[nj][1], acc[mi][nj], 0, 0, 0);
      }

    if (k0 < 11) __builtin_amdgcn_s_barrier();
  }
#undef STAGE

  // epilogue: scale + RNE bf16 pack, 8B store per quad (lines still filled
  // by lanes {L,L+16,L+32,L+48} x 2 mi-halves)
  const float inv = 1.0f / 768.0f;
  unsigned short* w2 = ws2b + (size_t)s * (NB * NB);
#pragma unroll
  for (int mi = 0; mi < 4; ++mi) {
#pragma unroll
    for (int nj = 0; nj < 4; ++nj) {
      f32x4 v = acc[mi][nj] * inv;
      u16x4 o;
#pragma unroll
      for (int r = 0; r < 4; ++r) {
        unsigned fu = __float_as_uint(v[r]);
        unsigned rr = fu + 0x7fffu + ((fu >> 16) & 1u);  // RNE
        o[r] = (unsigned short)(rr >> 16);
      }
      int mm = wm * 64 + nj * 16 + (lane & 15);
      int nn = wn * 64 + mi * 16 + (lane >> 4) * 4;
      *reinterpret_cast<u16x4*>(w2 + (size_t)mm * NB + nn) = o;
    }
  }
}

// ---------------------------------------------------------------------------
// Pass 3: transpose ws2b[s][m][n] (bf16) -> out[n][m][s] (fp32). Loads 8B
// (4 bf16) per lane, expands to f32 into the SAME swizzled f32 tile as R8;
// read/write-out side unchanged. Nontemporal final store.
// ---------------------------------------------------------------------------
__global__ __launch_bounds__(256) void pass3(const unsigned short* __restrict__ ws2b,
                                             float* __restrict__ out) {
  const int bid = blockIdx.x;        // 1024 blocks
  const int m   = bid & 127;
  const int st  = (bid >> 7) & 3;
  const int nt  = bid >> 9;          // 0..1
  const int t   = threadIdx.x;
  const int l16 = t & 15;
  const int hi4 = t >> 4;

  __shared__ float tile[64 * 64];    // swizzled [s][nchunk^((s>>2)&15)][4]

  const unsigned short* src =
      ws2b + ((size_t)(st * 64) * NB + m) * NB + nt * 64;
#pragma unroll
  for (int i = 0; i < 4; ++i) {
    int s_local = hi4 + 16 * i;
    uint2 u = *reinterpret_cast<const uint2*>(
        src + (size_t)s_local * (NB * NB) + l16 * 4);
    f32x4 v;
    v[0] = __uint_as_float((u.x & 0xffffu) << 16);
    v[1] = __uint_as_float((u.x >> 16) << 16);
    v[2] = __uint_as_float((u.y & 0xffffu) << 16);
    v[3] = __uint_as_float((u.y >> 16) << 16);
    int chunk = l16 ^ ((s_local >> 2) & 15);
    *reinterpret_cast<f32x4*>(&tile[s_local * 64 + chunk * 4]) = v;
  }
  __syncthreads();

  float* dst = out + ((size_t)(nt * 64) * NB + m) * S + st * 64;
#pragma unroll
  for (int i = 0; i < 4; ++i) {
    int n_local = hi4 + 16 * i;
    int cb      = (n_local >> 2) & 15;
    int ne      = n_local & 3;
    int s4      = l16 * 4;
    f32x4 v;
#pragma unroll
    for (int j = 0; j < 4; ++j) {
      int ss = s4 + j;
      v[j] = tile[ss * 64 + ((cb ^ ((ss >> 2) & 15)) << 2) + ne];
    }
    __builtin_nontemporal_store(
        v, reinterpret_cast<f32x4*>(dst + (size_t)n_local * (NB * S) + s4));
  }
}

extern "C" void kernel_launch(void* const* d_in, const int* in_sizes, int n_in,
                              void* d_out, int out_size, void* d_ws, size_t ws_size,
                              hipStream_t stream) {
  const float* x = (const float*)d_in[0];
  const float* y = (const float*)d_in[1];
  float* out = (float*)d_out;

  unsigned char* xb = (unsigned char*)d_ws;       // [128][256][768] fp8
  unsigned char* yb = xb + WS_TENSOR_B;
  unsigned short* ws2b =
      (unsigned short*)((char*)d_ws + 2 * WS_TENSOR_B);  // [256][128][128] bf16

  // zero xx/yy (atomicAdd target)
  hipMemsetAsync(out + XY_ELEMS, 0, (size_t)2 * XSQ_ELEMS * sizeof(float),
                 stream);
  pass1<<<1536, 256, 0, stream>>>(x, y, xb, yb, out);
  pass2<<<256, 256, 0, stream>>>(xb, yb, ws2b);
  pass3<<<1024, 256, 0, stream>>>(ws2b, out);
}